// Round 2
// baseline (4998.963 us; speedup 1.0000x reference)
//
#include <hip/hip_runtime.h>

typedef unsigned short u16;
typedef unsigned int u32;

// ---------- bf16 helpers (used only for ws-resident core/gate intermediates) ----------
__device__ __forceinline__ u16 f2bf(float f) {
  u32 u = __float_as_uint(f);
  u32 r = u + 0x7fffu + ((u >> 16) & 1u);
  return (u16)(r >> 16);
}
__device__ __forceinline__ void cvt8(uint4 u, float* f) {
  f[0] = __uint_as_float(u.x << 16);
  f[1] = __uint_as_float(u.x & 0xffff0000u);
  f[2] = __uint_as_float(u.y << 16);
  f[3] = __uint_as_float(u.y & 0xffff0000u);
  f[4] = __uint_as_float(u.z << 16);
  f[5] = __uint_as_float(u.z & 0xffff0000u);
  f[6] = __uint_as_float(u.w << 16);
  f[7] = __uint_as_float(u.w & 0xffff0000u);
}
__device__ __forceinline__ u32 pack2(float a, float b) {
  return (u32)f2bf(a) | ((u32)f2bf(b) << 16);
}

struct GatherSrc {
  const float* base[4];
  const int* idx[4];  // nullptr => identity (row index)
};

// ---------- pass 1: gathered concat GEMM -> core/gate (bf16 in ws) + BN stats ----------
// Block: 256 threads, 64 rows. Thread computes 4 rows x 8 cols (of 128 = core|gate).
template <int NSEG>
__global__ __launch_bounds__(256) void pass1_gemm(
    GatherSrc gs, const float* __restrict__ Wc, const float* __restrict__ Wg,
    u16* __restrict__ outC, u16* __restrict__ outG, float* __restrict__ stats,
    int R) {
  __shared__ float msg[64][68];      // [row][k within 64-chunk], padded
  __shared__ float wt[64][132];      // [k][core 0..63 | gate 64..127], padded
  __shared__ float sstat[2][2][64];  // [mat][sum/sumsq][col]
  __shared__ int rowidx[NSEG][64];

  const int t = threadIdx.x;
  const int e0 = blockIdx.x * 64;

  for (int i = t; i < 256; i += 256) ((float*)sstat)[i] = 0.0f;
  if (t < 64) {
    int rc = e0 + t;
    if (rc > R - 1) rc = R - 1;
#pragma unroll
    for (int sg = 0; sg < NSEG; ++sg) {
      const int* ip = gs.idx[sg];
      rowidx[sg][t] = ip ? ip[rc] : rc;
    }
  }

  float acc[4][8];
#pragma unroll
  for (int r = 0; r < 4; ++r)
#pragma unroll
    for (int j = 0; j < 8; ++j) acc[r][j] = 0.0f;

  const int cg = t & 15;        // col-group (8 cols) within 128
  const int r0 = (t >> 4) * 4;  // base row of the thread's 4 rows
  const int c8 = cg * 8;

  for (int kt = 0; kt < NSEG; ++kt) {
    __syncthreads();
    // stage msg chunk kt (gathered rows, 64 fp32 each): 1024 float4 slots
    {
      const float* base = gs.base[kt];
#pragma unroll
      for (int i = 0; i < 4; ++i) {
        int s = t + i * 256;
        int r = s >> 4, q4 = (s & 15) * 4;
        *(float4*)&msg[r][q4] =
            *(const float4*)(base + (size_t)rowidx[kt][r] * 64 + q4);
      }
    }
    // stage W tile: rows kt*64..+63 of Wc and Wg: 2048 float4 slots
    {
#pragma unroll
      for (int i = 0; i < 8; ++i) {
        int s = t + i * 256;
        int mat = s >> 10;
        int kk = (s >> 4) & 63;
        int q4 = (s & 15) * 4;
        const float* wsrc = (mat ? Wg : Wc) + (size_t)(kt * 64 + kk) * 64 + q4;
        *(float4*)&wt[kk][mat * 64 + q4] = *(const float4*)wsrc;
      }
    }
    __syncthreads();
    // compute: 4 rows x 8 cols, k over 64 in steps of 4
    for (int k = 0; k < 64; k += 4) {
      float a[4][4];
#pragma unroll
      for (int r = 0; r < 4; ++r)
        *(float4*)&a[r][0] = *(const float4*)&msg[r0 + r][k];
#pragma unroll
      for (int kk = 0; kk < 4; ++kk) {
        float w[8];
        *(float4*)&w[0] = *(const float4*)&wt[k + kk][c8];
        *(float4*)&w[4] = *(const float4*)&wt[k + kk][c8 + 4];
#pragma unroll
        for (int r = 0; r < 4; ++r) {
          float m = a[r][kk];
#pragma unroll
          for (int j = 0; j < 8; ++j) acc[r][j] = fmaf(m, w[j], acc[r][j]);
        }
      }
    }
  }

  // epilogue: store bf16 intermediates + accumulate stats
  const int mat = cg >> 3;
  const int cb = (cg & 7) * 8;  // col base within 64
  u16* outp = mat ? outG : outC;
  float ssum[8], ssq[8];
#pragma unroll
  for (int j = 0; j < 8; ++j) {
    ssum[j] = 0.0f;
    ssq[j] = 0.0f;
  }
#pragma unroll
  for (int r = 0; r < 4; ++r) {
    int row = e0 + r0 + r;
    if (row < R) {
      uint4 u;
      u.x = pack2(acc[r][0], acc[r][1]);
      u.y = pack2(acc[r][2], acc[r][3]);
      u.z = pack2(acc[r][4], acc[r][5]);
      u.w = pack2(acc[r][6], acc[r][7]);
      *(uint4*)(outp + (size_t)row * 64 + cb) = u;
#pragma unroll
      for (int j = 0; j < 8; ++j) {
        ssum[j] += acc[r][j];
        ssq[j] += acc[r][j] * acc[r][j];
      }
    }
  }
#pragma unroll
  for (int j = 0; j < 8; ++j) {
    atomicAdd(&sstat[mat][0][cb + j], ssum[j]);
    atomicAdd(&sstat[mat][1][cb + j], ssq[j]);
  }
  __syncthreads();
  {
    int m2 = t >> 7, s2 = (t >> 6) & 1, c = t & 63;
    atomicAdd(&stats[m2 * 128 + s2 * 64 + c], sstat[m2][s2][c]);
  }
}

// ---------- fold BN stats + gamma/beta into per-col scale/shift ----------
__global__ void statprep(float* __restrict__ stats, const float* __restrict__ gc,
                         const float* __restrict__ bc, const float* __restrict__ gg,
                         const float* __restrict__ bg, float rn) {
  int t = threadIdx.x;
  if (t >= 128) return;
  int mat = t >> 6, c = t & 63;
  float sum = stats[mat * 128 + c];
  float sumsq = stats[mat * 128 + 64 + c];
  float mean = sum * rn;
  float var = sumsq * rn - mean * mean;
  float inv = rsqrtf(var + 1e-5f);
  const float* gp = mat ? gg : gc;
  const float* bp = mat ? bg : bc;
  float scale = gp[c] * inv;
  float shift = bp[c] - mean * scale;
  stats[256 + mat * 128 + c] = scale;
  stats[256 + mat * 128 + 64 + c] = shift;
}

// ---------- pass 2: BN + silu*sigmoid + scatter-add into segment accumulator ----------
__global__ __launch_bounds__(256) void pass2_scatter(
    const u16* __restrict__ coreB, const u16* __restrict__ gateB,
    const float* __restrict__ stats, const int* __restrict__ seg,
    float* __restrict__ accum, int R) {
  int gid = blockIdx.x * 256 + threadIdx.x;
  if (gid >= R * 8) return;
  int r = gid >> 3;
  int cb = (gid & 7) * 8;
  uint4 uc = *(const uint4*)(coreB + (size_t)r * 64 + cb);
  uint4 ug = *(const uint4*)(gateB + (size_t)r * 64 + cb);
  float c[8], g[8];
  cvt8(uc, c);
  cvt8(ug, g);
  float scC[8], shC[8], scG[8], shG[8];
  *(float4*)&scC[0] = *(const float4*)&stats[256 + cb];
  *(float4*)&scC[4] = *(const float4*)&stats[256 + cb + 4];
  *(float4*)&shC[0] = *(const float4*)&stats[320 + cb];
  *(float4*)&shC[4] = *(const float4*)&stats[320 + cb + 4];
  *(float4*)&scG[0] = *(const float4*)&stats[384 + cb];
  *(float4*)&scG[4] = *(const float4*)&stats[384 + cb + 4];
  *(float4*)&shG[0] = *(const float4*)&stats[448 + cb];
  *(float4*)&shG[4] = *(const float4*)&stats[448 + cb + 4];
  int sg = seg[r];
  float* ap = accum + (size_t)sg * 64 + cb;
#pragma unroll
  for (int j = 0; j < 8; ++j) {
    float x = fmaf(c[j], scC[j], shC[j]);
    float sx = x / (1.0f + __expf(-x));  // silu
    float y = fmaf(g[j], scG[j], shG[j]);
    float sy = 1.0f / (1.0f + __expf(-y));  // sigmoid
    atomicAdd(ap + j, sx * sy);
  }
}

// ---------- pass 2 (angle stage): BN-gate + residual -> fp32 out ----------
__global__ __launch_bounds__(256) void pass2_final(
    const u16* __restrict__ coreB, const u16* __restrict__ gateB,
    const float* __restrict__ stats, const float* __restrict__ angle,
    float* __restrict__ outA, int R) {
  int gid = blockIdx.x * 256 + threadIdx.x;
  if (gid >= R * 8) return;
  int r = gid >> 3;
  int cb = (gid & 7) * 8;
  uint4 uc = *(const uint4*)(coreB + (size_t)r * 64 + cb);
  uint4 ug = *(const uint4*)(gateB + (size_t)r * 64 + cb);
  float c[8], g[8], a[8];
  cvt8(uc, c);
  cvt8(ug, g);
  *(float4*)&a[0] = *(const float4*)(angle + (size_t)r * 64 + cb);
  *(float4*)&a[4] = *(const float4*)(angle + (size_t)r * 64 + cb + 4);
  float scC[8], shC[8], scG[8], shG[8];
  *(float4*)&scC[0] = *(const float4*)&stats[256 + cb];
  *(float4*)&scC[4] = *(const float4*)&stats[256 + cb + 4];
  *(float4*)&shC[0] = *(const float4*)&stats[320 + cb];
  *(float4*)&shC[4] = *(const float4*)&stats[320 + cb + 4];
  *(float4*)&scG[0] = *(const float4*)&stats[384 + cb];
  *(float4*)&scG[4] = *(const float4*)&stats[384 + cb + 4];
  *(float4*)&shG[0] = *(const float4*)&stats[448 + cb];
  *(float4*)&shG[4] = *(const float4*)&stats[448 + cb + 4];
  float o[8];
#pragma unroll
  for (int j = 0; j < 8; ++j) {
    float x = fmaf(c[j], scC[j], shC[j]);
    float sx = x / (1.0f + __expf(-x));
    float y = fmaf(g[j], scG[j], shG[j]);
    float sy = 1.0f / (1.0f + __expf(-y));
    o[j] = sx * sy + a[j];
  }
  float* dst = outA + (size_t)r * 64 + cb;
  *(float4*)dst = *(float4*)&o[0];
  *(float4*)(dst + 4) = *(float4*)&o[4];
}

// ---------- small out-GEMM: dest = accum(fp32) @ W(fp32 64x64) + resid(fp32) ----------
__global__ __launch_bounds__(256) void outgemm(const float* __restrict__ accum,
                                               const float* __restrict__ W,
                                               const float* __restrict__ resid,
                                               float* __restrict__ dest, int R) {
  __shared__ float inl[64][68];
  __shared__ float wl[64][68];
  const int t = threadIdx.x;
  const int e0 = blockIdx.x * 64;
#pragma unroll
  for (int i = 0; i < 4; ++i) {  // stage W (64x64 fp32): 1024 float4 slots
    int s = t + i * 256;
    int kk = s >> 4, q4 = (s & 15) * 4;
    *(float4*)&wl[kk][q4] = *(const float4*)(W + (size_t)kk * 64 + q4);
  }
#pragma unroll
  for (int i = 0; i < 4; ++i) {  // stage input rows (fp32)
    int s = t + i * 256;
    int r = s >> 4, q4 = (s & 15) * 4;
    int row = e0 + r;
    if (row > R - 1) row = R - 1;
    *(float4*)&inl[r][q4] = *(const float4*)(accum + (size_t)row * 64 + q4);
  }
  __syncthreads();
  const int c4 = (t & 15) * 4;
  const int r0 = (t >> 4) * 4;
  float acc[4][4];
#pragma unroll
  for (int r = 0; r < 4; ++r)
#pragma unroll
    for (int j = 0; j < 4; ++j) acc[r][j] = 0.0f;
  for (int k = 0; k < 64; k += 4) {
    float a[4][4];
#pragma unroll
    for (int r = 0; r < 4; ++r)
      *(float4*)&a[r][0] = *(const float4*)&inl[r0 + r][k];
#pragma unroll
    for (int kk = 0; kk < 4; ++kk) {
      float w[4];
      *(float4*)&w[0] = *(const float4*)&wl[k + kk][c4];
#pragma unroll
      for (int r = 0; r < 4; ++r) {
        float m = a[r][kk];
#pragma unroll
        for (int j = 0; j < 4; ++j) acc[r][j] = fmaf(m, w[j], acc[r][j]);
      }
    }
  }
#pragma unroll
  for (int r = 0; r < 4; ++r) {
    int row = e0 + r0 + r;
    if (row < R) {
      float4 rv = *(const float4*)(resid + (size_t)row * 64 + c4);
      float4 o;
      o.x = acc[r][0] + rv.x;
      o.y = acc[r][1] + rv.y;
      o.z = acc[r][2] + rv.z;
      o.w = acc[r][3] + rv.w;
      *(float4*)(dest + (size_t)row * 64 + c4) = o;
    }
  }
}

extern "C" void kernel_launch(void* const* d_in, const int* in_sizes, int n_in,
                              void* d_out, int out_size, void* d_ws,
                              size_t ws_size, hipStream_t stream) {
  const float* vertex = (const float*)d_in[0];
  const float* edge = (const float*)d_in[1];
  const float* angle = (const float*)d_in[2];
  const int* eidx = (const int*)d_in[3];  // [2,E]: src then dst
  const int* kidx = (const int*)d_in[4];
  const int* iidx = (const int*)d_in[5];
  const int* jidx = (const int*)d_in[6];
  const float* WcA = (const float*)d_in[7];
  const float* WgA = (const float*)d_in[8];
  const float* WoA = (const float*)d_in[9];
  const float* WcB = (const float*)d_in[10];
  const float* WgB = (const float*)d_in[11];
  const float* WoB = (const float*)d_in[12];
  const float* WcC = (const float*)d_in[13];
  const float* WgC = (const float*)d_in[14];
  const float* g_ac = (const float*)d_in[15];
  const float* g_ag = (const float*)d_in[16];
  const float* g_bc = (const float*)d_in[17];
  const float* g_bg = (const float*)d_in[18];
  const float* g_nc = (const float*)d_in[19];
  const float* g_ng = (const float*)d_in[20];
  const float* b_ac = (const float*)d_in[21];
  const float* b_ag = (const float*)d_in[22];
  const float* b_bc = (const float*)d_in[23];
  const float* b_bg = (const float*)d_in[24];
  const float* b_nc = (const float*)d_in[25];
  const float* b_ng = (const float*)d_in[26];

  const int N = in_sizes[0] / 64;
  const int E = in_sizes[1] / 64;
  const int T = in_sizes[2] / 64;

  float* outV = (float*)d_out;
  float* outE = outV + (size_t)N * 64;
  float* outA = outE + (size_t)E * 64;

  // workspace layout: bf16 core/gate (max(E,T) rows) + shared fp32 accumulator
  // (max(N,E) rows; stage-A accum consumed before stage-B accum written) + stats
  size_t RT = (size_t)(E > T ? E : T);
  size_t RM = (size_t)(N > E ? N : E);
  u16* coreB = (u16*)d_ws;
  u16* gateB = coreB + RT * 64;
  float* accum = (float*)(gateB + RT * 64);  // RM x 64 fp32
  float* stats = accum + RM * 64;            // 3 stages x 512 floats
  float* statsA = stats;
  float* statsB = stats + 512;
  float* statsC = stats + 1024;

  // zero accum + stats (contiguous)
  size_t zbytes = (RM * 64 + 3 * 512) * 4;
  hipMemsetAsync(accum, 0, zbytes, stream);

  const int bE = (E + 63) / 64;
  const int bT = (T + 63) / 64;
  const int bN = (N + 63) / 64;
  const int sE = (int)(((size_t)E * 8 + 255) / 256);
  const int sT = (int)(((size_t)T * 8 + 255) / 256);

  // ---- stage A: AtomConv ----
  {
    GatherSrc gs;
    gs.base[0] = vertex; gs.idx[0] = eidx;      // vertex[src]
    gs.base[1] = edge;   gs.idx[1] = nullptr;   // edge[e]
    gs.base[2] = vertex; gs.idx[2] = eidx + E;  // vertex[dst]
    gs.base[3] = nullptr; gs.idx[3] = nullptr;
    pass1_gemm<3><<<bE, 256, 0, stream>>>(gs, WcA, WgA, coreB, gateB, statsA, E);
  }
  statprep<<<1, 128, 0, stream>>>(statsA, g_ac, b_ac, g_ag, b_ag, 1.0f / (float)E);
  pass2_scatter<<<sE, 256, 0, stream>>>(coreB, gateB, statsA, eidx, accum, E);
  outgemm<<<bN, 256, 0, stream>>>(accum, WoA, vertex, outV, N);

  // ---- stage B: BondConv ----
  // re-zero accum region used by stage B (N*64 already consumed; need E*64 zeros)
  hipMemsetAsync(accum, 0, (size_t)E * 64 * 4, stream);
  {
    GatherSrc gs;
    gs.base[0] = outV;  gs.idx[0] = jidx;  // v_new[j]
    gs.base[1] = edge;  gs.idx[1] = kidx;  // edge[k]
    gs.base[2] = edge;  gs.idx[2] = iidx;  // edge[i]
    gs.base[3] = angle; gs.idx[3] = nullptr;
    pass1_gemm<4><<<bT, 256, 0, stream>>>(gs, WcB, WgB, coreB, gateB, statsB, T);
  }
  statprep<<<1, 128, 0, stream>>>(statsB, g_bc, b_bc, g_bg, b_bg, 1.0f / (float)T);
  pass2_scatter<<<sT, 256, 0, stream>>>(coreB, gateB, statsB, kidx, accum, T);
  outgemm<<<bE, 256, 0, stream>>>(accum, WoB, edge, outE, E);

  // ---- stage C: AngleConv ----
  {
    GatherSrc gs;
    gs.base[0] = outV;  gs.idx[0] = jidx;  // v_new[j]
    gs.base[1] = outE;  gs.idx[1] = kidx;  // e_new[k]
    gs.base[2] = outE;  gs.idx[2] = iidx;  // e_new[i]
    gs.base[3] = angle; gs.idx[3] = nullptr;
    pass1_gemm<4><<<bT, 256, 0, stream>>>(gs, WcC, WgC, coreB, gateB, statsC, T);
  }
  statprep<<<1, 128, 0, stream>>>(statsC, g_nc, b_nc, g_ng, b_ng, 1.0f / (float)T);
  pass2_final<<<sT, 256, 0, stream>>>(coreB, gateB, statsC, angle, outA, T);
}